// Round 8
// baseline (466.399 us; speedup 1.0000x reference)
//
#include <hip/hip_runtime.h>
#include <hip/hip_bf16.h>

typedef __hip_bfloat16 bf16;
typedef __attribute__((ext_vector_type(4))) float f32x4;
typedef __attribute__((ext_vector_type(8))) short short8;

__device__ __forceinline__ float b2f(bf16 v) { return __bfloat162float(v); }
__device__ __forceinline__ ushort f2bu(float v)
{
    bf16 b = __float2bfloat16(v);
    return *(ushort*)&b;
}
__device__ __forceinline__ uint relu2(uint v)
{
    uint r = v;
    if (r & 0x8000u)     r &= 0xFFFF0000u;
    if (r & 0x80000000u) r &= 0x0000FFFFu;
    return r;
}
__device__ __forceinline__ uint packbf2(float a, float b)
{
    uint lo = f2bu(a), hi = f2bu(b);
    return lo | (hi << 16);
}

// async global -> LDS DMA, 16B per lane. LDS dest is WAVE-UNIFORM base
// (+lane*16 by HW); global src is per-lane.
typedef const __attribute__((address_space(1))) unsigned int* as1_u32;
typedef __attribute__((address_space(3))) unsigned int* as3_u32;
__device__ __forceinline__ void gld16(const void* g, uint* l)
{
    __builtin_amdgcn_global_load_lds((as1_u32)g, (as3_u32)l, 16, 0, 0);
}

// ===========================================================================
// initw_k: weight packing as ROW-TRANSPOSE. Unchanged from R3/R4.
// ===========================================================================
__global__ __launch_bounds__(256) void initw_k(
        const float* __restrict__ w_in, const float* __restrict__ w_h1,
        const float* __restrict__ w_h2, const float* __restrict__ w_h3,
        const float* __restrict__ r0w1, const float* __restrict__ r0w2,
        const float* __restrict__ r1w1, const float* __restrict__ r1w2,
        const float* __restrict__ emb,
        bf16* __restrict__ wp1, bf16* __restrict__ wpack2, bf16* __restrict__ wpack3,
        bf16* __restrict__ wp4, bf16* __restrict__ wpA0, bf16* __restrict__ wpA1,
        bf16* __restrict__ wpB0, bf16* __restrict__ wpB1,
        float* __restrict__ en, float* __restrict__ mse, int* __restrict__ hist,
        float* __restrict__ zpad)
{
    __shared__ ushort ls[12544];
    int b = blockIdx.x, t = threadIdx.x;

    if (b < 256) {                                   // wpack2: [tap50][cib8 16][co][cil8]
        const float* src = w_h1 + (size_t)b * 6272;
        for (int i = t; i < 6272; i += 256) ls[i] = f2bu(src[i]);
        __syncthreads();
        for (int e = t; e < 800; e += 256) {
            int tap = e >> 4, cib8 = e & 15;
            short8 v;
            #pragma unroll
            for (int cil = 0; cil < 8; ++cil)
                v[cil] = (tap < 49) ? (short)ls[(cib8 * 8 + cil) * 49 + tap] : (short)0;
            *(short8*)(wpack2 + ((size_t)(tap * 16 + cib8) * 256 + b) * 8) = v;
        }
        return;
    }
    if (b < 512) {                                   // wpack3: [tap50][cib8 32][co][cil8]
        int co = b - 256;
        const float* src = w_h2 + (size_t)co * 12544;
        for (int i = t; i < 12544; i += 256) ls[i] = f2bu(src[i]);
        __syncthreads();
        for (int e = t; e < 1600; e += 256) {
            int tap = e >> 5, cib8 = e & 31;
            short8 v;
            #pragma unroll
            for (int cil = 0; cil < 8; ++cil)
                v[cil] = (tap < 49) ? (short)ls[(cib8 * 8 + cil) * 49 + tap] : (short)0;
            *(short8*)(wpack3 + ((size_t)(tap * 32 + cib8) * 256 + co) * 8) = v;
        }
        return;
    }
    if (b < 768) {                                   // wp4: [tap9][cib8 32][co][cil8]
        int co = b - 512;
        const float* src = w_h3 + (size_t)co * 2304;
        for (int i = t; i < 2304; i += 256) ls[i] = f2bu(src[i]);
        __syncthreads();
        for (int e = t; e < 288; e += 256) {
            int tap = e >> 5, cib8 = e & 31;
            short8 v;
            #pragma unroll
            for (int cil = 0; cil < 8; ++cil)
                v[cil] = (short)ls[(cib8 * 8 + cil) * 9 + tap];
            *(short8*)(wp4 + ((size_t)(tap * 32 + cib8) * 256 + co) * 8) = v;
        }
        return;
    }
    if (b < 2816) {                                  // wpA0/wpA1: [tap3][cib8 32][co1024][cil8]
        int r = b - 768;
        int which = r >> 10;
        int co = r & 1023;
        const float* srcb = which ? r1w1 : r0w1;
        bf16* dstb = which ? wpA1 : wpA0;
        const float* src = srcb + (size_t)co * 768;
        for (int i = t; i < 768; i += 256) ls[i] = f2bu(src[i]);
        __syncthreads();
        if (t < 96) {
            int tap = t >> 5, cib8 = t & 31;
            short8 v;
            #pragma unroll
            for (int cil = 0; cil < 8; ++cil)
                v[cil] = (short)ls[(cib8 * 8 + cil) * 3 + tap];
            *(short8*)(dstb + ((size_t)(tap * 32 + cib8) * 1024 + co) * 8) = v;
        }
        return;
    }
    if (b < 3072) {                                  // wpB0/wpB1: [cib8 128][co][cil8]
        int r = b - 2816;
        int which = r >> 7;
        const float* srcb = which ? r1w2 : r0w2;
        bf16* dstb = which ? wpB1 : wpB0;
        int c = (r & 127) * 256 + t;
        int cib8 = c >> 8, co = c & 255;
        const float* s = srcb + (size_t)co * 1024 + cib8 * 8;
        short8 v;
        #pragma unroll
        for (int cil = 0; cil < 8; ++cil) v[cil] = (short)f2bu(s[cil]);
        *(short8*)(dstb + (size_t)c * 8) = v;
        return;
    }
    if (b < 3104) {                                  // wp1
        int i = (b - 3072) * 256 + t;
        int j = i & 7; int co = (i >> 3) & 127; int kb = i >> 10;
        int k = kb * 8 + j;
        wp1[i] = __float2bfloat16(k < 48 ? w_in[co * 48 + k] : 0.f);
        return;
    }
    if (b < 3106) {                                  // emb norms
        int row = (b - 3104) * 256 + t;
        const float4* e = (const float4*)(emb + (size_t)row * 256);
        float s = 0.f;
        for (int d4 = 0; d4 < 64; ++d4) {
            float4 v = e[d4];
            s += v.x * v.x + v.y * v.y + v.z * v.z + v.w * v.w;
        }
        en[row] = s;
        return;
    }
    // misc zero
    if (t == 0) mse[0] = 0.f;
    for (int i = t; i < 512; i += 256) hist[i] = 0;
    if (t < 64) zpad[t] = 0.f;
}

// ===========================================================================
// conv1 MFMA -> ci-BLOCKED bf16 h1c[img][ci16][px][16]. Unchanged.
// ===========================================================================
__global__ __launch_bounds__(256) void conv1m_k(const float* __restrict__ x,
        const bf16* __restrict__ wp1, const float* __restrict__ bias,
        bf16* __restrict__ h1c)
{
    int bid = blockIdx.x;
    int pxt = bid & 511, img = bid >> 9;
    int tr = pxt >> 4, tc = pxt & 15;
    int oh0 = tr * 8, ow0 = tc * 16;
    const float* xi = x + (size_t)img * 786432;
    bf16* oT = h1c + (size_t)img * 8388608;

    int t = threadIdx.x;
    int wave = t >> 6, lane = t & 63;
    int quad = lane >> 4, l15 = lane & 15;

    __shared__ ushort xs[4 * 640];
    __shared__ ushort ot[128 * 136];

    int ihb = oh0 * 2 - 1, iwb = ow0 * 2 - 1;
    for (int i = t; i < 1836; i += 256) {
        int ci = i / 612; int r1 = i - ci * 612;
        int ihl = r1 / 34, iwl = r1 - ihl * 34;
        int ih = ihb + ihl, iw = iwb + iwl;
        float v = 0.f;
        if ((unsigned)ih < 512u && (unsigned)iw < 512u)
            v = xi[ci * 262144 + ih * 512 + iw];
        xs[ci * 640 + ihl * 35 + iwl] = f2bu(v);
    }
    for (int i = t; i < 640; i += 256) xs[3 * 640 + i] = 0;
    __syncthreads();

    f32x4 zero = {0.f, 0.f, 0.f, 0.f};
    f32x4 acc[8][2];
    #pragma unroll
    for (int m = 0; m < 8; ++m) { acc[m][0] = zero; acc[m][1] = zero; }

    int ci_b = quad >> 1;
    int kh0 = (quad & 1) * 2;
    int iwl0 = 2 * l15;

    #pragma unroll
    for (int ks = 0; ks < 2; ++ks) {
        union { short8 v; uint u[4]; } b[2];
        #pragma unroll
        for (int nt = 0; nt < 2; ++nt) {
            int py = wave * 2 + nt;
            int base = (ks * 2 + ci_b) * 640 + (2 * py + kh0) * 35 + iwl0;
            b[nt].u[0] = *(const uint*)&xs[base];
            b[nt].u[1] = *(const uint*)&xs[base + 2];
            b[nt].u[2] = *(const uint*)&xs[base + 35];
            b[nt].u[3] = *(const uint*)&xs[base + 37];
        }
        const bf16* abase = wp1 + ((size_t)(ks * 4 + quad) * 128 + l15) * 8;
        #pragma unroll
        for (int m = 0; m < 8; ++m) {
            short8 a = *(const short8*)(abase + m * 16 * 8);
            acc[m][0] = __builtin_amdgcn_mfma_f32_16x16x32_bf16(a, b[0].v, acc[m][0], 0, 0, 0);
            acc[m][1] = __builtin_amdgcn_mfma_f32_16x16x32_bf16(a, b[1].v, acc[m][1], 0, 0, 0);
        }
    }

    #pragma unroll
    for (int m = 0; m < 8; ++m) {
        int cobase = m * 16 + quad * 4;
        float b0 = bias[cobase], b1 = bias[cobase + 1];
        float b2 = bias[cobase + 2], b3 = bias[cobase + 3];
        #pragma unroll
        for (int nt = 0; nt < 2; ++nt) {
            int pxl = (wave * 2 + nt) * 16 + l15;
            uint w0 = packbf2(fmaxf(b0 + acc[m][nt][0], 0.f),
                              fmaxf(b1 + acc[m][nt][1], 0.f));
            uint w1 = packbf2(fmaxf(b2 + acc[m][nt][2], 0.f),
                              fmaxf(b3 + acc[m][nt][3], 0.f));
            *(uint*)&ot[pxl * 136 + cobase]     = w0;
            *(uint*)&ot[pxl * 136 + cobase + 2] = w1;
        }
    }
    __syncthreads();
    {
        int pxl = t >> 1, half = t & 1;
        int oh = oh0 + (pxl >> 4), ow = ow0 + (pxl & 15);
        size_t px = (size_t)(oh * 256 + ow);
        #pragma unroll
        for (int cb = 0; cb < 4; ++cb) {
            int c16 = half * 4 + cb;
            const uint4* src = (const uint4*)&ot[pxl * 136 + c16 * 16];
            uint4* dst = (uint4*)(oT + ((size_t)c16 * 65536 + px) * 16);
            dst[0] = src[0];
            dst[1] = src[1];
        }
    }
}

// ===========================================================================
// implicit-GEMM MFMA 7x7 s4 p2 conv, v11:
//  - v9 base (DMA staging, dbuf, XOR swizzle, full tap unroll).
//  - NEW: A-operand register RING, depth 3 (A[3][4]): consume A[tp%3],
//    prefetch A(tp+3) into the just-freed slot AFTER the MFMAs
//    (hazard-ordered) -> ~2 iterations (~160-240 cyc) of cover for the
//    ~200-cyc L2 A-load latency. B stays dist-1 (LDS latency is short).
//    All ring indices compile-time (full unroll) -> no scratch (rule #20).
// MODE: 0 = fused bias+relu -> blocked bf16, 3 = f32 slices (no atomics).
// ===========================================================================
template <int IH, int OH, int CI, int SPLIT, int MODE>
__global__ __launch_bounds__(256, 2) void conv_mfma11_k(
        const bf16* __restrict__ inC, const bf16* __restrict__ wpack,
        const float* __restrict__ bias, float* __restrict__ outA,
        bf16* __restrict__ outT, const float* __restrict__ zpad)
{
    constexpr int TPD = OH / 8;
    constexpr int NT = TPD * TPD;
    constexpr int CPB = (CI / 16) / SPLIT;
    constexpr int CIB8 = CI / 8;
    constexpr int NPX = IH * IH;
    constexpr int SLOTS = 2496;

    int bid = blockIdx.x;
    int pxt = bid % NT;
    int rest = bid / NT;
    int img = rest & 7;
    int split = rest >> 3;
    int oh0 = (pxt / TPD) * 8, ow0 = (pxt % TPD) * 8;

    int t = threadIdx.x;
    int wave = t >> 6, lane = t & 63;
    int quad = lane >> 4, l15 = lane & 15;

    const bf16* inb = inC + (size_t)img * ((size_t)NPX * CI);

    __shared__ __align__(16) uint bufA[SLOTS * 4];
    __shared__ __align__(16) uint bufB[SLOTS * 4];

    f32x4 zero = {0.f, 0.f, 0.f, 0.f};
    f32x4 acc[4][4];
    #pragma unroll
    for (int a = 0; a < 4; ++a)
        #pragma unroll
        for (int b = 0; b < 4; ++b) acc[a][b] = zero;

    int ihb = oh0 * 4 - 2, iwb = ow0 * 4 - 2;
    int qxl = l15 & 7, pyl = l15 >> 3;
    int tap_par = quad >> 1, ci_half = quad & 1;

    int  srel[10];
    bool sval[10];
    #pragma unroll
    for (int it = 0; it < 10; ++it) {
        int sb = (it < 9) ? it * 256 + wave * 64 : 2304 + wave * 64;
        int p  = sb + lane;
        int pb = p << 4;
        int lb = pb ^ (((pb >> 7) & 7) << 4);
        int j  = lb >> 4;
        int pos = j >> 1, half = j & 1;
        int r = pos / 35, c = pos - r * 35;
        int ih = ihb + r, iw = iwb + c;
        sval[it] = (j < 2450) && ((unsigned)ih < (unsigned)IH)
                   && ((unsigned)iw < (unsigned)IH);
        srel[it] = (ih * IH + iw) * 16 + half * 8;
    }

    auto stage = [&](int ch, uint* dst) {
        const bf16* cbp = inb + (size_t)ch * NPX * 16;
        #pragma unroll
        for (int it = 0; it < 10; ++it) {
            if (it == 9 && wave >= 3) continue;
            int sb = (it < 9) ? it * 256 + wave * 64 : 2304 + wave * 64;
            const void* src = sval[it] ? (const void*)(cbp + srel[it])
                                       : (const void*)zpad;
            gld16(src, dst + sb * 4);
        }
    };

    int rbase = pyl * 4480 + qxl * 128 + ci_half * 16;
    int d1  = tap_par * 32;
    int d29 = tap_par * 928;

    auto compute = [&](int ch, const uint* cbuf) {
        const bf16* ab = wpack
            + ((size_t)(ch * 2 + ci_half) * 256 + wave * 64 + l15) * 8
            + (size_t)tap_par * (CIB8 * 2048);
        short8 A[3][4], B[2][4];
        auto loadA = [&](int tn, short8* dst) {
            const bf16* at = ab + (size_t)(2 * tn) * (CIB8 * 2048);
            #pragma unroll
            for (int ct = 0; ct < 4; ++ct)
                dst[ct] = *(const short8*)(at + ct * 128);
        };
        auto loadB = [&](int tn, short8* dst) {
            const int kh0 = (2 * tn) / 7, kw0 = (2 * tn) % 7;
            const int cE  = (kh0 * 35 + kw0) * 32;
            int dsel = (tn == 24) ? 0 : ((kw0 == 6) ? d29 : d1);
            int lbb  = rbase + cE + dsel;
            #pragma unroll
            for (int pt = 0; pt < 4; ++pt) {
                int lb = lbb + pt * 8960;
                int pb = lb ^ (((lb >> 7) & 7) << 4);
                dst[pt] = *(const short8*)((const char*)cbuf + pb);
            }
        };
        loadA(0, A[0]); loadA(1, A[1]); loadA(2, A[2]);
        loadB(0, B[0]);
        __builtin_amdgcn_s_setprio(1);
        #pragma unroll
        for (int tp = 0; tp < 25; ++tp) {
            if (tp < 24) loadB(tp + 1, B[(tp + 1) % 2]);
            #pragma unroll
            for (int pt = 0; pt < 4; ++pt)
                #pragma unroll
                for (int ct = 0; ct < 4; ++ct)
                    acc[ct][pt] = __builtin_amdgcn_mfma_f32_16x16x32_bf16(
                        A[tp % 3][ct], B[tp % 2][pt], acc[ct][pt], 0, 0, 0);
            if (tp < 22) loadA(tp + 3, A[tp % 3]);   // just-freed slot
        }
        __builtin_amdgcn_s_setprio(0);
    };

    if constexpr (CPB == 1) {
        stage(split, bufA);
        __syncthreads();
        compute(split, bufA);
    } else {
        stage(split * CPB, bufA);
        __syncthreads();
        for (int cc2 = 0; cc2 < CPB; cc2 += 2) {
            stage(split * CPB + cc2 + 1, bufB);
            compute(split * CPB + cc2, bufA);
            __syncthreads();
            if (cc2 + 2 < CPB) stage(split * CPB + cc2 + 2, bufA);
            compute(split * CPB + cc2 + 1, bufB);
            __syncthreads();
        }
    }

    #pragma unroll
    for (int ct = 0; ct < 4; ++ct) {
        int cobase = wave * 64 + ct * 16 + quad * 4;
        #pragma unroll
        for (int pt = 0; pt < 4; ++pt) {
            int px = pt * 16 + l15;
            int oh = oh0 + (px >> 3), ow = ow0 + (px & 7);
            int pxg = oh * OH + ow;
            #pragma unroll
            for (int r = 0; r < 4; ++r) {
                int co = cobase + r;
                float v = acc[ct][pt][r];
                if (MODE == 3) {
                    outA[(size_t)split * ((size_t)8 * OH * OH * 256)
                         + (size_t)img * (OH * OH * 256)
                         + (size_t)co * (OH * OH) + pxg] = v;
                } else {
                    float o = fmaxf(bias[co] + v, 0.f);
                    size_t base = (size_t)img * (size_t)(OH * OH * 256);
                    outT[base + ((size_t)(co >> 4) * (OH * OH) + pxg) * 16 + (co & 15)]
                        = __float2bfloat16(o);
                }
            }
        }
    }
}

// combine3: h3 = relu(bias + sum of 8 f32 slices) -> NHWC bf16. grid 2048.
// (R3 elementwise version — ledger-proven faster than the LDS-transpose
//  grid-128 variant, which starved half the CUs; p3 is read-dominated and
//  these reads are perfectly coalesced.)
__global__ void combine3_k(const float* __restrict__ p3, const float* __restrict__ bias,
                           bf16* __restrict__ h3T)
{
    int idx = blockIdx.x * 256 + threadIdx.x;      // 524,288
    int px = idx & 255;
    int co = (idx >> 8) & 255;
    int img = idx >> 16;
    float v = bias[co];
    #pragma unroll
    for (int s = 0; s < 8; ++s) v += p3[(size_t)s * 524288 + idx];
    v = fmaxf(v, 0.f);
    h3T[((size_t)img * 256 + px) * 256 + co] = __float2bfloat16(v);
}

// ===========================================================================
// conv4 MFMA: 3x3 s2 p1, 256->256 ch, 16->8, NHWC bf16, relu. grid 32.
// ===========================================================================
__global__ __launch_bounds__(256) void conv4m_k(const bf16* __restrict__ h3T,
        const bf16* __restrict__ wp4, const float* __restrict__ bias,
        bf16* __restrict__ h4T)
{
    int bid = blockIdx.x;
    int img = bid >> 2, cog = bid & 3;
    int t = threadIdx.x;
    int wave = t >> 6, lane = t & 63;
    int quad = lane >> 4, l15 = lane & 15;

    __shared__ uint pt[16 * 325];

    for (int i = t; i < 16 * 325; i += 256) pt[i] = 0;

    f32x4 zero = {0.f, 0.f, 0.f, 0.f};
    f32x4 acc[4];
    #pragma unroll
    for (int b = 0; b < 4; ++b) acc[b] = zero;

    const bf16* inb = h3T + (size_t)img * 65536;

    for (int ch = 0; ch < 8; ++ch) {
        __syncthreads();
        for (int e = t; e < 4096; e += 256) {
            int cp = e & 15, px = e >> 4;
            int py = px >> 4, qx = px & 15;
            uint v = *(const uint*)(inb + (size_t)px * 256 + ch * 32 + cp * 2);
            pt[cp * 325 + (py + 1) * 18 + qx + 1] = v;
        }
        __syncthreads();

        for (int tap = 0; tap < 9; ++tap) {
            int kh = tap / 3, kw = tap - kh * 3;
            const bf16* abase = wp4 + ((size_t)((tap * 32 + ch * 4 + quad) * 256)
                                       + cog * 64 + wave * 16 + l15) * 8;
            short8 a = *(const short8*)abase;
            #pragma unroll
            for (int pq = 0; pq < 4; ++pq) {
                int pyo = 2 * pq + (l15 >> 3);
                int ipos = (2 * pyo + kh) * 18 + 2 * (l15 & 7) + kw;
                union { short8 v; uint u[4]; } b;
                b.u[0] = pt[(quad * 4 + 0) * 325 + ipos];
                b.u[1] = pt[(quad * 4 + 1) * 325 + ipos];
                b.u[2] = pt[(quad * 4 + 2) * 325 + ipos];
                b.u[3] = pt[(quad * 4 + 3) * 325 + ipos];
                acc[pq] = __builtin_amdgcn_mfma_f32_16x16x32_bf16(
                    a, b.v, acc[pq], 0, 0, 0);
            }
        }
    }

    int cobase = cog * 64 + wave * 16 + quad * 4;
    #pragma unroll
    for (int pq = 0; pq < 4; ++pq) {
        int px = pq * 16 + l15;
        #pragma unroll
        for (int r = 0; r < 4; ++r) {
            int co = cobase + r;
            float v = fmaxf(bias[co] + acc[pq][r], 0.f);
            h4T[((size_t)img * 64 + px) * 256 + co] = __float2bfloat16(v);
        }
    }
}

// ===========================================================================
// res-a MFMA: t1 = conv1x3(relu(h)), 256->1024. grid 64.
// ===========================================================================
__global__ __launch_bounds__(256) void resam_k(const bf16* __restrict__ hT,
        const bf16* __restrict__ wpA, bf16* __restrict__ t1T)
{
    int bid = blockIdx.x;
    int img = bid >> 3, g = bid & 7;
    int t = threadIdx.x;
    int wave = t >> 6, lane = t & 63;
    int quad = lane >> 4, l15 = lane & 15;

    __shared__ uint ph[128 * 81];

    for (int i = t; i < 128 * 81; i += 256) ph[i] = 0;
    __syncthreads();
    const bf16* inb = hT + (size_t)img * 16384;
    for (int e = t; e < 8192; e += 256) {
        int cp = e & 127, px = e >> 7;
        uint v = relu2(*(const uint*)(inb + (size_t)px * 256 + cp * 2));
        ph[cp * 81 + (px >> 3) * 10 + (px & 7) + 1] = v;
    }
    __syncthreads();

    f32x4 zero = {0.f, 0.f, 0.f, 0.f};
    f32x4 acc[2][4];
    #pragma unroll
    for (int a = 0; a < 2; ++a)
        #pragma unroll
        for (int b = 0; b < 4; ++b) acc[a][b] = zero;

    for (int ch = 0; ch < 8; ++ch) {
        for (int tap = 0; tap < 3; ++tap) {
            const bf16* abase = wpA + ((size_t)(tap * 32 + ch * 4 + quad) * 1024
                                       + g * 128 + wave * 32 + l15) * 8;
            short8 a[2];
            #pragma unroll
            for (int ct = 0; ct < 2; ++ct)
                a[ct] = *(const short8*)(abase + ct * 16 * 8);
            #pragma unroll
            for (int pq = 0; pq < 4; ++pq) {
                int py = 2 * pq + (l15 >> 3);
                int pos = py * 10 + (l15 & 7) + tap;
                union { short8 v; uint u[4]; } b;
                b.u[0] = ph[(ch * 16 + quad * 4 + 0) * 81 + pos];
                b.u[1] = ph[(ch * 16 + quad * 4 + 1) * 81 + pos];
                b.u[2] = ph[(ch * 16 + quad * 4 + 2) * 81 + pos];
                b.u[3] = ph[(ch * 16 + quad * 4 + 3) * 81 + pos];
                #pragma unroll
                for (int ct = 0; ct < 2; ++ct)
                    acc[ct][pq] = __builtin_amdgcn_mfma_f32_16x16x32_bf16(
                        a[ct], b.v, acc[ct][pq], 0, 0, 0);
            }
        }
    }

    #pragma unroll
    for (int ct = 0; ct < 2; ++ct) {
        int cobase = g * 128 + wave * 32 + ct * 16 + quad * 4;
        #pragma unroll
        for (int pq = 0; pq < 4; ++pq) {
            int px = pq * 16 + l15;
            #pragma unroll
            for (int r = 0; r < 4; ++r)
                t1T[((size_t)img * 64 + px) * 1024 + cobase + r]
                    = __float2bfloat16(acc[ct][pq][r]);
        }
    }
}

// ===========================================================================
// res-b MFMA: h_new = h_old + conv1x1(relu(t1)), 1024->256. grid 32.
// ===========================================================================
__global__ __launch_bounds__(256) void resbm_k(const bf16* __restrict__ holdT,
        const bf16* __restrict__ t1T, const bf16* __restrict__ wpB,
        bf16* __restrict__ hnewT)
{
    int bid = blockIdx.x;
    int img = bid >> 2, cog = bid & 3;
    int t = threadIdx.x;
    int wave = t >> 6, lane = t & 63;
    int quad = lane >> 4, l15 = lane & 15;

    __shared__ uint pb[256 * 65];

    f32x4 zero = {0.f, 0.f, 0.f, 0.f};
    f32x4 acc[4];
    #pragma unroll
    for (int b = 0; b < 4; ++b) acc[b] = zero;

    const bf16* inb = t1T + (size_t)img * 65536;

    for (int s = 0; s < 2; ++s) {
        __syncthreads();
        for (int e = t; e < 16384; e += 256) {
            int cp = e & 255, px = e >> 8;
            uint v = relu2(*(const uint*)(inb + (size_t)px * 1024 + s * 512 + cp * 2));
            pb[cp * 65 + px] = v;
        }
        __syncthreads();

        for (int chl = 0; chl < 16; ++chl) {
            int ch = s * 16 + chl;
            const bf16* abase = wpB + ((size_t)(ch * 4 + quad) * 256
                                       + cog * 64 + wave * 16 + l15) * 8;
            short8 a = *(const short8*)abase;
            #pragma unroll
            for (int pq = 0; pq < 4; ++pq) {
                int px = pq * 16 + l15;
                union { short8 v; uint u[4]; } b;
                b.u[0] = pb[(chl * 16 + quad * 4 + 0) * 65 + px];
                b.u[1] = pb[(chl * 16 + quad * 4 + 1) * 65 + px];
                b.u[2] = pb[(chl * 16 + quad * 4 + 2) * 65 + px];
                b.u[3] = pb[(chl * 16 + quad * 4 + 3) * 65 + px];
                acc[pq] = __builtin_amdgcn_mfma_f32_16x16x32_bf16(
                    a, b.v, acc[pq], 0, 0, 0);
            }
        }
    }

    int cobase = cog * 64 + wave * 16 + quad * 4;
    #pragma unroll
    for (int pq = 0; pq < 4; ++pq) {
        int px = pq * 16 + l15;
        #pragma unroll
        for (int r = 0; r < 4; ++r) {
            int co = cobase + r;
            size_t o = ((size_t)img * 64 + px) * 256 + co;
            float v = b2f(holdT[o]) + acc[pq][r];
            hnewT[o] = __float2bfloat16(v);
        }
    }
}

// ===========================================================================
// VQ: 128 blocks x 4 rows. min-reduce via wave shuffles.
// ===========================================================================
__global__ __launch_bounds__(256) void vq_k(const bf16* __restrict__ h6T,
        const float* __restrict__ emb, const float* __restrict__ en,
        float* __restrict__ out, float* __restrict__ mse_acc, int* __restrict__ hist)
{
    int row0 = blockIdx.x * 4;
    int t = threadIdx.x;
    int wave = t >> 6, lane = t & 63;
    __shared__ float lat[4][256];
    __shared__ float swd[4][4];
    __shared__ int   swi[4][4];
    __shared__ int   fidx[4];
    __shared__ float smse[4];

    for (int e = t; e < 1024; e += 256) {
        int r = e >> 8, c = e & 255;
        lat[r][c] = fmaxf(b2f(h6T[(size_t)(row0 + r) * 256 + c]), 0.f);
    }
    __syncthreads();

    float a0[4] = {0.f, 0.f, 0.f, 0.f}, a1[4] = {0.f, 0.f, 0.f, 0.f};
    const float4* e0 = (const float4*)(emb + (size_t)t * 256);
    const float4* e1 = (const float4*)(emb + (size_t)(t + 256) * 256);
    for (int d4 = 0; d4 < 64; ++d4) {
        float4 v0 = e0[d4], v1 = e1[d4];
        #pragma unroll
        for (int r = 0; r < 4; ++r) {
            float l0 = lat[r][d4 * 4], l1 = lat[r][d4 * 4 + 1];
            float l2 = lat[r][d4 * 4 + 2], l3 = lat[r][d4 * 4 + 3];
            a0[r] += l0 * v0.x + l1 * v0.y + l2 * v0.z + l3 * v0.w;
            a1[r] += l0 * v1.x + l1 * v1.y + l2 * v1.z + l3 * v1.w;
        }
    }
    float en0 = en[t], en1 = en[t + 256];
    float bd[4]; int bi[4];
    #pragma unroll
    for (int r = 0; r < 4; ++r) {
        float d0 = en0 - 2.f * a0[r], d1v = en1 - 2.f * a1[r];
        bd[r] = d0; bi[r] = t;
        if (d1v < bd[r]) { bd[r] = d1v; bi[r] = t + 256; }
    }
    #pragma unroll
    for (int s = 1; s < 64; s <<= 1) {
        #pragma unroll
        for (int r = 0; r < 4; ++r) {
            float od = __shfl_xor(bd[r], s);
            int   oi = __shfl_xor(bi[r], s);
            if (od < bd[r] || (od == bd[r] && oi < bi[r])) { bd[r] = od; bi[r] = oi; }
        }
    }
    if (lane == 0) {
        #pragma unroll
        for (int r = 0; r < 4; ++r) { swd[wave][r] = bd[r]; swi[wave][r] = bi[r]; }
    }
    __syncthreads();
    if (t < 4) {
        float best = swd[0][t]; int bidx = swi[0][t];
        for (int w = 1; w < 4; ++w) {
            float od = swd[w][t]; int oi = swi[w][t];
            if (od < best || (od == best && oi < bidx)) { best = od; bidx = oi; }
        }
        fidx[t] = bidx;
    }
    __syncthreads();

    float msel = 0.f;
    #pragma unroll
    for (int r = 0; r < 4; ++r) {
        int row = row0 + r;
        int b = row >> 6, y = (row >> 3) & 7, xx = row & 7;
        float q = emb[(size_t)fidx[r] * 256 + t];
        out[((size_t)(b * 256 + t) * 8 + y) * 8 + xx] = q;
        float diff = q - lat[r][t];
        msel += diff * diff;
    }
    #pragma unroll
    for (int s = 1; s < 64; s <<= 1) msel += __shfl_xor(msel, s);
    if (lane == 0) smse[wave] = msel;
    __syncthreads();
    if (t == 0) atomicAdd(mse_acc, smse[0] + smse[1] + smse[2] + smse[3]);
    if (t < 4) atomicAdd(&hist[fidx[t]], 1);
}

__global__ void final_k(const float* __restrict__ mse_acc, const int* __restrict__ hist,
                        float* __restrict__ out)
{
    __shared__ float sh[512];
    int t = threadIdx.x;
    float p = (float)hist[t] / 512.f;
    sh[t] = p * logf(p + 1e-10f);
    __syncthreads();
    for (int s = 256; s > 0; s >>= 1) {
        if (t < s) sh[t] += sh[t + s];
        __syncthreads();
    }
    if (t == 0) {
        float loss = 2.f * mse_acc[0] / (512.f * 256.f);
        float perp = expf(-sh[0]);
        out[131072] = loss;
        out[131073] = perp;
    }
}

// ===========================================================================
extern "C" void kernel_launch(void* const* d_in, const int* in_sizes, int n_in,
                              void* d_out, int out_size, void* d_ws, size_t ws_size,
                              hipStream_t stream)
{
    const float* x    = (const float*)d_in[0];
    const float* w_in = (const float*)d_in[1];
    const float* b_in = (const float*)d_in[2];
    const float* w_h1 = (const float*)d_in[3];
    const float* b_h1 = (const float*)d_in[4];
    const float* w_h2 = (const float*)d_in[5];
    const float* b_h2 = (const float*)d_in[6];
    const float* w_h3 = (const float*)d_in[7];
    const float* b_h3 = (const float*)d_in[8];
    const float* r0w1 = (const float*)d_in[9];
    const float* r0w2 = (const float*)d_in[10];
    const float* r1w1 = (const float*)d_in[11];
    const float* r1w2 = (const float*)d_in[12];
    const float* emb  = (const float*)d_in[13];
    float* out = (float*)d_out;

    char* ws = (char*)d_ws;
    size_t off = 0;
    auto alloc = [&](size_t bytes) -> void* {
        void* p = ws + off;
        off += (bytes + 255) & ~(size_t)255;
        return p;
    };

    float* en  = (float*)alloc(512 * 4);
    float* mse = (float*)alloc(256);
    int*  hist = (int*)alloc(512 * 4);
    float* zpad = (float*)alloc(256);
    float* p3  = (float*)alloc(4194304ull * 4);    // 8 f32 slices, 16.8 MB
    bf16* h3T  = (bf16*)alloc(524288ull * 2);
    bf16* h4T  = (bf16*)alloc(131072ull * 2);
    bf16* t1T  = (bf16*)alloc(524288ull * 2);
    bf16* h5T  = (bf16*)alloc(131072ull * 2);
    bf16* h6T  = (bf16*)alloc(131072ull * 2);
    bf16* wp1  = (bf16*)alloc(8192ull * 2);
    bf16* wpack2 = (bf16*)alloc(1638400ull * 2);
    bf16* wpack3 = (bf16*)alloc(3276800ull * 2);
    bf16* wp4  = (bf16*)alloc(589824ull * 2);
    bf16* wpA0 = (bf16*)alloc(786432ull * 2);
    bf16* wpA1 = (bf16*)alloc(786432ull * 2);
    bf16* wpB0 = (bf16*)alloc(262144ull * 2);
    bf16* wpB1 = (bf16*)alloc(262144ull * 2);
    bf16* h2c  = (bf16*)alloc(8388608ull * 2);     // [8][16 blk][4096 px][16]
    size_t base_end = off;

    const size_t H1F_B = 8388608ull * 8 * 2;       // batched h1c, 134 MB
    size_t needT1 = base_end + H1F_B + 4096;
    bf16* h1c;
    int tier;
    if (ws_size >= needT1) {
        h1c = (bf16*)alloc(H1F_B);
        tier = 1;
    } else {
        h1c = (bf16*)alloc(8388608ull * 2);
        tier = 2;
    }

    initw_k<<<3107, 256, 0, stream>>>(w_in, w_h1, w_h2, w_h3, r0w1, r0w2, r1w1, r1w2,
        emb, wp1, wpack2, wpack3, wp4, wpA0, wpA1, wpB0, wpB1, en, mse, hist, zpad);

    if (tier == 1) {
        conv1m_k<<<4096, 256, 0, stream>>>(x, wp1, b_in, h1c);
        conv_mfma11_k<256, 64, 128, 1, 0><<<512, 256, 0, stream>>>(
            h1c, wpack2, b_h1, nullptr, h2c, zpad);
    } else {
        for (int n = 0; n < 8; ++n) {
            conv1m_k<<<512, 256, 0, stream>>>(x + (size_t)n * 786432, wp1, b_in, h1c);
            conv_mfma11_k<256, 64, 128, 1, 0><<<64, 256, 0, stream>>>(
                h1c, wpack2, b_h1, nullptr, h2c + (size_t)n * 1048576, zpad);
        }
    }

    conv_mfma11_k<64, 16, 256, 8, 3><<<256, 256, 0, stream>>>(
        h2c, wpack3, nullptr, p3, nullptr, zpad);
    combine3_k<<<2048, 256, 0, stream>>>(p3, b_h2, h3T);

    conv4m_k<<<32, 256, 0, stream>>>(h3T, wp4, b_h3, h4T);
    resam_k<<<64, 256, 0, stream>>>(h4T, wpA0, t1T);
    resbm_k<<<32, 256, 0, stream>>>(h4T, t1T, wpB0, h5T);
    resam_k<<<64, 256, 0, stream>>>(h5T, wpA1, t1T);
    resbm_k<<<32, 256, 0, stream>>>(h5T, t1T, wpB1, h6T);

    vq_k<<<128, 256, 0, stream>>>(h6T, emb, en, out, mse, hist);
    final_k<<<1, 512, 0, stream>>>(mse, hist, out);
}

// Round 9
// 443.685 us; speedup vs baseline: 1.0512x; 1.0512x over previous
//
#include <hip/hip_runtime.h>
#include <hip/hip_bf16.h>

typedef __hip_bfloat16 bf16;
typedef __attribute__((ext_vector_type(4))) float f32x4;
typedef __attribute__((ext_vector_type(8))) short short8;

__device__ __forceinline__ float b2f(bf16 v) { return __bfloat162float(v); }
__device__ __forceinline__ ushort f2bu(float v)
{
    bf16 b = __float2bfloat16(v);
    return *(ushort*)&b;
}
__device__ __forceinline__ uint relu2(uint v)
{
    uint r = v;
    if (r & 0x8000u)     r &= 0xFFFF0000u;
    if (r & 0x80000000u) r &= 0x0000FFFFu;
    return r;
}
__device__ __forceinline__ uint packbf2(float a, float b)
{
    uint lo = f2bu(a), hi = f2bu(b);
    return lo | (hi << 16);
}

// async global -> LDS DMA, 16B per lane. LDS dest is WAVE-UNIFORM base
// (+lane*16 by HW); global src is per-lane.
typedef const __attribute__((address_space(1))) unsigned int* as1_u32;
typedef __attribute__((address_space(3))) unsigned int* as3_u32;
__device__ __forceinline__ void gld16(const void* g, uint* l)
{
    __builtin_amdgcn_global_load_lds((as1_u32)g, (as3_u32)l, 16, 0, 0);
}

// ===========================================================================
// initw_k: weight packing as ROW-TRANSPOSE. Unchanged from R3/R4.
// ===========================================================================
__global__ __launch_bounds__(256) void initw_k(
        const float* __restrict__ w_in, const float* __restrict__ w_h1,
        const float* __restrict__ w_h2, const float* __restrict__ w_h3,
        const float* __restrict__ r0w1, const float* __restrict__ r0w2,
        const float* __restrict__ r1w1, const float* __restrict__ r1w2,
        const float* __restrict__ emb,
        bf16* __restrict__ wp1, bf16* __restrict__ wpack2, bf16* __restrict__ wpack3,
        bf16* __restrict__ wp4, bf16* __restrict__ wpA0, bf16* __restrict__ wpA1,
        bf16* __restrict__ wpB0, bf16* __restrict__ wpB1,
        float* __restrict__ en, float* __restrict__ mse, int* __restrict__ hist,
        float* __restrict__ zpad)
{
    __shared__ ushort ls[12544];
    int b = blockIdx.x, t = threadIdx.x;

    if (b < 256) {                                   // wpack2: [tap50][cib8 16][co][cil8]
        const float* src = w_h1 + (size_t)b * 6272;
        for (int i = t; i < 6272; i += 256) ls[i] = f2bu(src[i]);
        __syncthreads();
        for (int e = t; e < 800; e += 256) {
            int tap = e >> 4, cib8 = e & 15;
            short8 v;
            #pragma unroll
            for (int cil = 0; cil < 8; ++cil)
                v[cil] = (tap < 49) ? (short)ls[(cib8 * 8 + cil) * 49 + tap] : (short)0;
            *(short8*)(wpack2 + ((size_t)(tap * 16 + cib8) * 256 + b) * 8) = v;
        }
        return;
    }
    if (b < 512) {                                   // wpack3: [tap50][cib8 32][co][cil8]
        int co = b - 256;
        const float* src = w_h2 + (size_t)co * 12544;
        for (int i = t; i < 12544; i += 256) ls[i] = f2bu(src[i]);
        __syncthreads();
        for (int e = t; e < 1600; e += 256) {
            int tap = e >> 5, cib8 = e & 31;
            short8 v;
            #pragma unroll
            for (int cil = 0; cil < 8; ++cil)
                v[cil] = (tap < 49) ? (short)ls[(cib8 * 8 + cil) * 49 + tap] : (short)0;
            *(short8*)(wpack3 + ((size_t)(tap * 32 + cib8) * 256 + co) * 8) = v;
        }
        return;
    }
    if (b < 768) {                                   // wp4: [tap9][cib8 32][co][cil8]
        int co = b - 512;
        const float* src = w_h3 + (size_t)co * 2304;
        for (int i = t; i < 2304; i += 256) ls[i] = f2bu(src[i]);
        __syncthreads();
        for (int e = t; e < 288; e += 256) {
            int tap = e >> 5, cib8 = e & 31;
            short8 v;
            #pragma unroll
            for (int cil = 0; cil < 8; ++cil)
                v[cil] = (short)ls[(cib8 * 8 + cil) * 9 + tap];
            *(short8*)(wp4 + ((size_t)(tap * 32 + cib8) * 256 + co) * 8) = v;
        }
        return;
    }
    if (b < 2816) {                                  // wpA0/wpA1: [tap3][cib8 32][co1024][cil8]
        int r = b - 768;
        int which = r >> 10;
        int co = r & 1023;
        const float* srcb = which ? r1w1 : r0w1;
        bf16* dstb = which ? wpA1 : wpA0;
        const float* src = srcb + (size_t)co * 768;
        for (int i = t; i < 768; i += 256) ls[i] = f2bu(src[i]);
        __syncthreads();
        if (t < 96) {
            int tap = t >> 5, cib8 = t & 31;
            short8 v;
            #pragma unroll
            for (int cil = 0; cil < 8; ++cil)
                v[cil] = (short)ls[(cib8 * 8 + cil) * 3 + tap];
            *(short8*)(dstb + ((size_t)(tap * 32 + cib8) * 1024 + co) * 8) = v;
        }
        return;
    }
    if (b < 3072) {                                  // wpB0/wpB1: [cib8 128][co][cil8]
        int r = b - 2816;
        int which = r >> 7;
        const float* srcb = which ? r1w2 : r0w2;
        bf16* dstb = which ? wpB1 : wpB0;
        int c = (r & 127) * 256 + t;
        int cib8 = c >> 8, co = c & 255;
        const float* s = srcb + (size_t)co * 1024 + cib8 * 8;
        short8 v;
        #pragma unroll
        for (int cil = 0; cil < 8; ++cil) v[cil] = (short)f2bu(s[cil]);
        *(short8*)(dstb + (size_t)c * 8) = v;
        return;
    }
    if (b < 3104) {                                  // wp1
        int i = (b - 3072) * 256 + t;
        int j = i & 7; int co = (i >> 3) & 127; int kb = i >> 10;
        int k = kb * 8 + j;
        wp1[i] = __float2bfloat16(k < 48 ? w_in[co * 48 + k] : 0.f);
        return;
    }
    if (b < 3106) {                                  // emb norms
        int row = (b - 3104) * 256 + t;
        const float4* e = (const float4*)(emb + (size_t)row * 256);
        float s = 0.f;
        for (int d4 = 0; d4 < 64; ++d4) {
            float4 v = e[d4];
            s += v.x * v.x + v.y * v.y + v.z * v.z + v.w * v.w;
        }
        en[row] = s;
        return;
    }
    // misc zero
    if (t == 0) mse[0] = 0.f;
    for (int i = t; i < 512; i += 256) hist[i] = 0;
    if (t < 64) zpad[t] = 0.f;
}

// ===========================================================================
// conv1 MFMA -> ci-BLOCKED bf16 h1c[img][ci16][px][16]. Unchanged.
// ===========================================================================
__global__ __launch_bounds__(256) void conv1m_k(const float* __restrict__ x,
        const bf16* __restrict__ wp1, const float* __restrict__ bias,
        bf16* __restrict__ h1c)
{
    int bid = blockIdx.x;
    int pxt = bid & 511, img = bid >> 9;
    int tr = pxt >> 4, tc = pxt & 15;
    int oh0 = tr * 8, ow0 = tc * 16;
    const float* xi = x + (size_t)img * 786432;
    bf16* oT = h1c + (size_t)img * 8388608;

    int t = threadIdx.x;
    int wave = t >> 6, lane = t & 63;
    int quad = lane >> 4, l15 = lane & 15;

    __shared__ ushort xs[4 * 640];
    __shared__ ushort ot[128 * 136];

    int ihb = oh0 * 2 - 1, iwb = ow0 * 2 - 1;
    for (int i = t; i < 1836; i += 256) {
        int ci = i / 612; int r1 = i - ci * 612;
        int ihl = r1 / 34, iwl = r1 - ihl * 34;
        int ih = ihb + ihl, iw = iwb + iwl;
        float v = 0.f;
        if ((unsigned)ih < 512u && (unsigned)iw < 512u)
            v = xi[ci * 262144 + ih * 512 + iw];
        xs[ci * 640 + ihl * 35 + iwl] = f2bu(v);
    }
    for (int i = t; i < 640; i += 256) xs[3 * 640 + i] = 0;
    __syncthreads();

    f32x4 zero = {0.f, 0.f, 0.f, 0.f};
    f32x4 acc[8][2];
    #pragma unroll
    for (int m = 0; m < 8; ++m) { acc[m][0] = zero; acc[m][1] = zero; }

    int ci_b = quad >> 1;
    int kh0 = (quad & 1) * 2;
    int iwl0 = 2 * l15;

    #pragma unroll
    for (int ks = 0; ks < 2; ++ks) {
        union { short8 v; uint u[4]; } b[2];
        #pragma unroll
        for (int nt = 0; nt < 2; ++nt) {
            int py = wave * 2 + nt;
            int base = (ks * 2 + ci_b) * 640 + (2 * py + kh0) * 35 + iwl0;
            b[nt].u[0] = *(const uint*)&xs[base];
            b[nt].u[1] = *(const uint*)&xs[base + 2];
            b[nt].u[2] = *(const uint*)&xs[base + 35];
            b[nt].u[3] = *(const uint*)&xs[base + 37];
        }
        const bf16* abase = wp1 + ((size_t)(ks * 4 + quad) * 128 + l15) * 8;
        #pragma unroll
        for (int m = 0; m < 8; ++m) {
            short8 a = *(const short8*)(abase + m * 16 * 8);
            acc[m][0] = __builtin_amdgcn_mfma_f32_16x16x32_bf16(a, b[0].v, acc[m][0], 0, 0, 0);
            acc[m][1] = __builtin_amdgcn_mfma_f32_16x16x32_bf16(a, b[1].v, acc[m][1], 0, 0, 0);
        }
    }

    #pragma unroll
    for (int m = 0; m < 8; ++m) {
        int cobase = m * 16 + quad * 4;
        float b0 = bias[cobase], b1 = bias[cobase + 1];
        float b2 = bias[cobase + 2], b3 = bias[cobase + 3];
        #pragma unroll
        for (int nt = 0; nt < 2; ++nt) {
            int pxl = (wave * 2 + nt) * 16 + l15;
            uint w0 = packbf2(fmaxf(b0 + acc[m][nt][0], 0.f),
                              fmaxf(b1 + acc[m][nt][1], 0.f));
            uint w1 = packbf2(fmaxf(b2 + acc[m][nt][2], 0.f),
                              fmaxf(b3 + acc[m][nt][3], 0.f));
            *(uint*)&ot[pxl * 136 + cobase]     = w0;
            *(uint*)&ot[pxl * 136 + cobase + 2] = w1;
        }
    }
    __syncthreads();
    {
        int pxl = t >> 1, half = t & 1;
        int oh = oh0 + (pxl >> 4), ow = ow0 + (pxl & 15);
        size_t px = (size_t)(oh * 256 + ow);
        #pragma unroll
        for (int cb = 0; cb < 4; ++cb) {
            int c16 = half * 4 + cb;
            const uint4* src = (const uint4*)&ot[pxl * 136 + c16 * 16];
            uint4* dst = (uint4*)(oT + ((size_t)c16 * 65536 + px) * 16);
            dst[0] = src[0];
            dst[1] = src[1];
        }
    }
}

// ===========================================================================
// implicit-GEMM MFMA 7x7 s4 p2 conv, v9r: the R4/R7 passing kernel (dist-1
// pipeline, DMA staging, dbuf, XOR swizzle, full tap unroll) with ONE
// addition: MODE 0 epilogue stores packed as uint2 (co&15 = quad*4+r is
// contiguous -> 4x 2B scalar stores become 1x 8B store).
// MODE: 0 = fused bias+relu -> blocked bf16, 3 = f32 slices (no atomics).
// A-ring depth>1 CLOSED (R8: depth-3 regressed +4us, FETCH +13%).
// ===========================================================================
template <int IH, int OH, int CI, int SPLIT, int MODE>
__global__ __launch_bounds__(256, 2) void conv_mfma9_k(
        const bf16* __restrict__ inC, const bf16* __restrict__ wpack,
        const float* __restrict__ bias, float* __restrict__ outA,
        bf16* __restrict__ outT, const float* __restrict__ zpad)
{
    constexpr int TPD = OH / 8;
    constexpr int NT = TPD * TPD;
    constexpr int CPB = (CI / 16) / SPLIT;
    constexpr int CIB8 = CI / 8;
    constexpr int NPX = IH * IH;
    constexpr int SLOTS = 2496;

    int bid = blockIdx.x;
    int pxt = bid % NT;
    int rest = bid / NT;
    int img = rest & 7;
    int split = rest >> 3;
    int oh0 = (pxt / TPD) * 8, ow0 = (pxt % TPD) * 8;

    int t = threadIdx.x;
    int wave = t >> 6, lane = t & 63;
    int quad = lane >> 4, l15 = lane & 15;

    const bf16* inb = inC + (size_t)img * ((size_t)NPX * CI);

    __shared__ __align__(16) uint bufA[SLOTS * 4];
    __shared__ __align__(16) uint bufB[SLOTS * 4];

    f32x4 zero = {0.f, 0.f, 0.f, 0.f};
    f32x4 acc[4][4];
    #pragma unroll
    for (int a = 0; a < 4; ++a)
        #pragma unroll
        for (int b = 0; b < 4; ++b) acc[a][b] = zero;

    int ihb = oh0 * 4 - 2, iwb = ow0 * 4 - 2;
    int qxl = l15 & 7, pyl = l15 >> 3;
    int tap_par = quad >> 1, ci_half = quad & 1;

    int  srel[10];
    bool sval[10];
    #pragma unroll
    for (int it = 0; it < 10; ++it) {
        int sb = (it < 9) ? it * 256 + wave * 64 : 2304 + wave * 64;
        int p  = sb + lane;
        int pb = p << 4;
        int lb = pb ^ (((pb >> 7) & 7) << 4);
        int j  = lb >> 4;
        int pos = j >> 1, half = j & 1;
        int r = pos / 35, c = pos - r * 35;
        int ih = ihb + r, iw = iwb + c;
        sval[it] = (j < 2450) && ((unsigned)ih < (unsigned)IH)
                   && ((unsigned)iw < (unsigned)IH);
        srel[it] = (ih * IH + iw) * 16 + half * 8;
    }

    auto stage = [&](int ch, uint* dst) {
        const bf16* cbp = inb + (size_t)ch * NPX * 16;
        #pragma unroll
        for (int it = 0; it < 10; ++it) {
            if (it == 9 && wave >= 3) continue;
            int sb = (it < 9) ? it * 256 + wave * 64 : 2304 + wave * 64;
            const void* src = sval[it] ? (const void*)(cbp + srel[it])
                                       : (const void*)zpad;
            gld16(src, dst + sb * 4);
        }
    };

    int rbase = pyl * 4480 + qxl * 128 + ci_half * 16;
    int d1  = tap_par * 32;
    int d29 = tap_par * 928;

    auto compute = [&](int ch, const uint* cbuf) {
        const bf16* ab = wpack
            + ((size_t)(ch * 2 + ci_half) * 256 + wave * 64 + l15) * 8
            + (size_t)tap_par * (CIB8 * 2048);
        __builtin_amdgcn_s_setprio(1);
        short8 aC[4], bC[4], aN[4], bN[4];
        {
            #pragma unroll
            for (int ct = 0; ct < 4; ++ct)
                aC[ct] = *(const short8*)(ab + ct * 128);
            int lbb = rbase + d1;
            #pragma unroll
            for (int pt = 0; pt < 4; ++pt) {
                int lb = lbb + pt * 8960;
                int pb = lb ^ (((lb >> 7) & 7) << 4);
                bC[pt] = *(const short8*)((const char*)cbuf + pb);
            }
        }
        #pragma unroll
        for (int tp = 0; tp < 25; ++tp) {
            if (tp < 24) {
                const int tn  = tp + 1;
                const int kh0 = (2 * tn) / 7, kw0 = (2 * tn) % 7;
                const int cE  = (kh0 * 35 + kw0) * 32;
                int dsel = (tn == 24) ? 0 : ((kw0 == 6) ? d29 : d1);
                int lbb  = rbase + cE + dsel;
                const bf16* at = ab + (size_t)(2 * tn) * (CIB8 * 2048);
                #pragma unroll
                for (int ct = 0; ct < 4; ++ct)
                    aN[ct] = *(const short8*)(at + ct * 128);
                #pragma unroll
                for (int pt = 0; pt < 4; ++pt) {
                    int lb = lbb + pt * 8960;
                    int pb = lb ^ (((lb >> 7) & 7) << 4);
                    bN[pt] = *(const short8*)((const char*)cbuf + pb);
                }
            }
            #pragma unroll
            for (int pt = 0; pt < 4; ++pt)
                #pragma unroll
                for (int ct = 0; ct < 4; ++ct)
                    acc[ct][pt] = __builtin_amdgcn_mfma_f32_16x16x32_bf16(
                        aC[ct], bC[pt], acc[ct][pt], 0, 0, 0);
            if (tp < 24) {
                #pragma unroll
                for (int i = 0; i < 4; ++i) { aC[i] = aN[i]; bC[i] = bN[i]; }
            }
        }
        __builtin_amdgcn_s_setprio(0);
    };

    if constexpr (CPB == 1) {
        stage(split, bufA);
        __syncthreads();
        compute(split, bufA);
    } else {
        stage(split * CPB, bufA);
        __syncthreads();
        for (int cc2 = 0; cc2 < CPB; cc2 += 2) {
            stage(split * CPB + cc2 + 1, bufB);
            compute(split * CPB + cc2, bufA);
            __syncthreads();
            if (cc2 + 2 < CPB) stage(split * CPB + cc2 + 2, bufA);
            compute(split * CPB + cc2 + 1, bufB);
            __syncthreads();
        }
    }

    #pragma unroll
    for (int ct = 0; ct < 4; ++ct) {
        int cobase = wave * 64 + ct * 16 + quad * 4;
        #pragma unroll
        for (int pt = 0; pt < 4; ++pt) {
            int px = pt * 16 + l15;
            int oh = oh0 + (px >> 3), ow = ow0 + (px & 7);
            int pxg = oh * OH + ow;
            if (MODE == 3) {
                #pragma unroll
                for (int r = 0; r < 4; ++r) {
                    int co = cobase + r;
                    outA[(size_t)split * ((size_t)8 * OH * OH * 256)
                         + (size_t)img * (OH * OH * 256)
                         + (size_t)co * (OH * OH) + pxg] = acc[ct][pt][r];
                }
            } else {
                float o0 = fmaxf(bias[cobase]     + acc[ct][pt][0], 0.f);
                float o1 = fmaxf(bias[cobase + 1] + acc[ct][pt][1], 0.f);
                float o2 = fmaxf(bias[cobase + 2] + acc[ct][pt][2], 0.f);
                float o3 = fmaxf(bias[cobase + 3] + acc[ct][pt][3], 0.f);
                uint2 w;
                w.x = packbf2(o0, o1);
                w.y = packbf2(o2, o3);
                size_t base = (size_t)img * (size_t)(OH * OH * 256);
                *(uint2*)(outT + base
                          + ((size_t)(wave * 4 + ct) * (OH * OH) + pxg) * 16
                          + quad * 4) = w;
            }
        }
    }
}

// combine3: h3 = relu(bias + sum of 8 f32 slices) -> NHWC bf16. grid 2048.
// (R3 elementwise — ledger-proven best; p3 reads dominate and are coalesced.)
__global__ void combine3_k(const float* __restrict__ p3, const float* __restrict__ bias,
                           bf16* __restrict__ h3T)
{
    int idx = blockIdx.x * 256 + threadIdx.x;      // 524,288
    int px = idx & 255;
    int co = (idx >> 8) & 255;
    int img = idx >> 16;
    float v = bias[co];
    #pragma unroll
    for (int s = 0; s < 8; ++s) v += p3[(size_t)s * 524288 + idx];
    v = fmaxf(v, 0.f);
    h3T[((size_t)img * 256 + px) * 256 + co] = __float2bfloat16(v);
}

// ===========================================================================
// conv4 MFMA: 3x3 s2 p1, 256->256 ch, 16->8, NHWC bf16, relu. grid 32.
// ===========================================================================
__global__ __launch_bounds__(256) void conv4m_k(const bf16* __restrict__ h3T,
        const bf16* __restrict__ wp4, const float* __restrict__ bias,
        bf16* __restrict__ h4T)
{
    int bid = blockIdx.x;
    int img = bid >> 2, cog = bid & 3;
    int t = threadIdx.x;
    int wave = t >> 6, lane = t & 63;
    int quad = lane >> 4, l15 = lane & 15;

    __shared__ uint pt[16 * 325];

    for (int i = t; i < 16 * 325; i += 256) pt[i] = 0;

    f32x4 zero = {0.f, 0.f, 0.f, 0.f};
    f32x4 acc[4];
    #pragma unroll
    for (int b = 0; b < 4; ++b) acc[b] = zero;

    const bf16* inb = h3T + (size_t)img * 65536;

    for (int ch = 0; ch < 8; ++ch) {
        __syncthreads();
        for (int e = t; e < 4096; e += 256) {
            int cp = e & 15, px = e >> 4;
            int py = px >> 4, qx = px & 15;
            uint v = *(const uint*)(inb + (size_t)px * 256 + ch * 32 + cp * 2);
            pt[cp * 325 + (py + 1) * 18 + qx + 1] = v;
        }
        __syncthreads();

        for (int tap = 0; tap < 9; ++tap) {
            int kh = tap / 3, kw = tap - kh * 3;
            const bf16* abase = wp4 + ((size_t)((tap * 32 + ch * 4 + quad) * 256)
                                       + cog * 64 + wave * 16 + l15) * 8;
            short8 a = *(const short8*)abase;
            #pragma unroll
            for (int pq = 0; pq < 4; ++pq) {
                int pyo = 2 * pq + (l15 >> 3);
                int ipos = (2 * pyo + kh) * 18 + 2 * (l15 & 7) + kw;
                union { short8 v; uint u[4]; } b;
                b.u[0] = pt[(quad * 4 + 0) * 325 + ipos];
                b.u[1] = pt[(quad * 4 + 1) * 325 + ipos];
                b.u[2] = pt[(quad * 4 + 2) * 325 + ipos];
                b.u[3] = pt[(quad * 4 + 3) * 325 + ipos];
                acc[pq] = __builtin_amdgcn_mfma_f32_16x16x32_bf16(
                    a, b.v, acc[pq], 0, 0, 0);
            }
        }
    }

    int cobase = cog * 64 + wave * 16 + quad * 4;
    #pragma unroll
    for (int pq = 0; pq < 4; ++pq) {
        int px = pq * 16 + l15;
        #pragma unroll
        for (int r = 0; r < 4; ++r) {
            int co = cobase + r;
            float v = fmaxf(bias[co] + acc[pq][r], 0.f);
            h4T[((size_t)img * 64 + px) * 256 + co] = __float2bfloat16(v);
        }
    }
}

// ===========================================================================
// res-a MFMA: t1 = conv1x3(relu(h)), 256->1024.
// v3: g-split 8 -> 16 (grid 128; 25% -> 50% CU coverage). Each block: 64 co
// (g*64 + wave*16), one A-frag per tap, acc[4].
// ===========================================================================
__global__ __launch_bounds__(256) void resam_k(const bf16* __restrict__ hT,
        const bf16* __restrict__ wpA, bf16* __restrict__ t1T)
{
    int bid = blockIdx.x;
    int img = bid >> 4, g = bid & 15;
    int t = threadIdx.x;
    int wave = t >> 6, lane = t & 63;
    int quad = lane >> 4, l15 = lane & 15;

    __shared__ uint ph[128 * 81];

    for (int i = t; i < 128 * 81; i += 256) ph[i] = 0;
    __syncthreads();
    const bf16* inb = hT + (size_t)img * 16384;
    for (int e = t; e < 8192; e += 256) {
        int cp = e & 127, px = e >> 7;
        uint v = relu2(*(const uint*)(inb + (size_t)px * 256 + cp * 2));
        ph[cp * 81 + (px >> 3) * 10 + (px & 7) + 1] = v;
    }
    __syncthreads();

    f32x4 zero = {0.f, 0.f, 0.f, 0.f};
    f32x4 acc[4];
    #pragma unroll
    for (int b = 0; b < 4; ++b) acc[b] = zero;

    for (int ch = 0; ch < 8; ++ch) {
        for (int tap = 0; tap < 3; ++tap) {
            const bf16* abase = wpA + ((size_t)(tap * 32 + ch * 4 + quad) * 1024
                                       + g * 64 + wave * 16 + l15) * 8;
            short8 a = *(const short8*)abase;
            #pragma unroll
            for (int pq = 0; pq < 4; ++pq) {
                int py = 2 * pq + (l15 >> 3);
                int pos = py * 10 + (l15 & 7) + tap;
                union { short8 v; uint u[4]; } b;
                b.u[0] = ph[(ch * 16 + quad * 4 + 0) * 81 + pos];
                b.u[1] = ph[(ch * 16 + quad * 4 + 1) * 81 + pos];
                b.u[2] = ph[(ch * 16 + quad * 4 + 2) * 81 + pos];
                b.u[3] = ph[(ch * 16 + quad * 4 + 3) * 81 + pos];
                acc[pq] = __builtin_amdgcn_mfma_f32_16x16x32_bf16(
                    a, b.v, acc[pq], 0, 0, 0);
            }
        }
    }

    int cobase = g * 64 + wave * 16 + quad * 4;
    #pragma unroll
    for (int pq = 0; pq < 4; ++pq) {
        int px = pq * 16 + l15;
        #pragma unroll
        for (int r = 0; r < 4; ++r)
            t1T[((size_t)img * 64 + px) * 1024 + cobase + r]
                = __float2bfloat16(acc[pq][r]);
    }
}

// ===========================================================================
// res-b MFMA: h_new = h_old + conv1x1(relu(t1)), 1024->256.
// v3: px-split x2 (grid 64; 12.5% -> 25% CU coverage). Each block: 64 co x
// 32 px; LDS 33.8 KB; clean halo-free split (1x1 conv).
// ===========================================================================
__global__ __launch_bounds__(256) void resbm_k(const bf16* __restrict__ holdT,
        const bf16* __restrict__ t1T, const bf16* __restrict__ wpB,
        bf16* __restrict__ hnewT)
{
    int bid = blockIdx.x;
    int img = bid >> 3, cog = (bid >> 1) & 3, ph = bid & 1;
    int t = threadIdx.x;
    int wave = t >> 6, lane = t & 63;
    int quad = lane >> 4, l15 = lane & 15;

    __shared__ uint pb[256 * 33];

    f32x4 zero = {0.f, 0.f, 0.f, 0.f};
    f32x4 acc[2];
    acc[0] = zero; acc[1] = zero;

    const bf16* inb = t1T + (size_t)img * 65536 + (size_t)ph * 32 * 1024;

    for (int s = 0; s < 2; ++s) {
        __syncthreads();
        for (int e = t; e < 8192; e += 256) {
            int cp = e & 255, pxl = e >> 8;
            uint v = relu2(*(const uint*)(inb + (size_t)pxl * 1024 + s * 512 + cp * 2));
            pb[cp * 33 + pxl] = v;
        }
        __syncthreads();

        for (int chl = 0; chl < 16; ++chl) {
            int ch = s * 16 + chl;
            const bf16* abase = wpB + ((size_t)(ch * 4 + quad) * 256
                                       + cog * 64 + wave * 16 + l15) * 8;
            short8 a = *(const short8*)abase;
            #pragma unroll
            for (int pq = 0; pq < 2; ++pq) {
                int pxl = pq * 16 + l15;
                union { short8 v; uint u[4]; } b;
                b.u[0] = pb[(chl * 16 + quad * 4 + 0) * 33 + pxl];
                b.u[1] = pb[(chl * 16 + quad * 4 + 1) * 33 + pxl];
                b.u[2] = pb[(chl * 16 + quad * 4 + 2) * 33 + pxl];
                b.u[3] = pb[(chl * 16 + quad * 4 + 3) * 33 + pxl];
                acc[pq] = __builtin_amdgcn_mfma_f32_16x16x32_bf16(
                    a, b.v, acc[pq], 0, 0, 0);
            }
        }
    }

    int cobase = cog * 64 + wave * 16 + quad * 4;
    #pragma unroll
    for (int pq = 0; pq < 2; ++pq) {
        int px = ph * 32 + pq * 16 + l15;
        #pragma unroll
        for (int r = 0; r < 4; ++r) {
            int co = cobase + r;
            size_t o = ((size_t)img * 64 + px) * 256 + co;
            float v = b2f(holdT[o]) + acc[pq][r];
            hnewT[o] = __float2bfloat16(v);
        }
    }
}

// ===========================================================================
// VQ v3: 256 blocks x 2 rows (was 128 x 4; 50% -> 100% CU coverage).
// emb stays L2/L3-resident so the doubled re-read is ~2us.
// ===========================================================================
__global__ __launch_bounds__(256) void vq_k(const bf16* __restrict__ h6T,
        const float* __restrict__ emb, const float* __restrict__ en,
        float* __restrict__ out, float* __restrict__ mse_acc, int* __restrict__ hist)
{
    int row0 = blockIdx.x * 2;
    int t = threadIdx.x;
    int wave = t >> 6, lane = t & 63;
    __shared__ float lat[2][256];
    __shared__ float swd[4][2];
    __shared__ int   swi[4][2];
    __shared__ int   fidx[2];
    __shared__ float smse[4];

    for (int e = t; e < 512; e += 256) {
        int r = e >> 8, c = e & 255;
        lat[r][c] = fmaxf(b2f(h6T[(size_t)(row0 + r) * 256 + c]), 0.f);
    }
    __syncthreads();

    float a0[2] = {0.f, 0.f}, a1[2] = {0.f, 0.f};
    const float4* e0 = (const float4*)(emb + (size_t)t * 256);
    const float4* e1 = (const float4*)(emb + (size_t)(t + 256) * 256);
    for (int d4 = 0; d4 < 64; ++d4) {
        float4 v0 = e0[d4], v1 = e1[d4];
        #pragma unroll
        for (int r = 0; r < 2; ++r) {
            float l0 = lat[r][d4 * 4], l1 = lat[r][d4 * 4 + 1];
            float l2 = lat[r][d4 * 4 + 2], l3 = lat[r][d4 * 4 + 3];
            a0[r] += l0 * v0.x + l1 * v0.y + l2 * v0.z + l3 * v0.w;
            a1[r] += l0 * v1.x + l1 * v1.y + l2 * v1.z + l3 * v1.w;
        }
    }
    float en0 = en[t], en1 = en[t + 256];
    float bd[2]; int bi[2];
    #pragma unroll
    for (int r = 0; r < 2; ++r) {
        float d0 = en0 - 2.f * a0[r], d1v = en1 - 2.f * a1[r];
        bd[r] = d0; bi[r] = t;
        if (d1v < bd[r]) { bd[r] = d1v; bi[r] = t + 256; }
    }
    #pragma unroll
    for (int s = 1; s < 64; s <<= 1) {
        #pragma unroll
        for (int r = 0; r < 2; ++r) {
            float od = __shfl_xor(bd[r], s);
            int   oi = __shfl_xor(bi[r], s);
            if (od < bd[r] || (od == bd[r] && oi < bi[r])) { bd[r] = od; bi[r] = oi; }
        }
    }
    if (lane == 0) {
        #pragma unroll
        for (int r = 0; r < 2; ++r) { swd[wave][r] = bd[r]; swi[wave][r] = bi[r]; }
    }
    __syncthreads();
    if (t < 2) {
        float best = swd[0][t]; int bidx = swi[0][t];
        for (int w = 1; w < 4; ++w) {
            float od = swd[w][t]; int oi = swi[w][t];
            if (od < best || (od == best && oi < bidx)) { best = od; bidx = oi; }
        }
        fidx[t] = bidx;
    }
    __syncthreads();

    float msel = 0.f;
    #pragma unroll
    for (int r = 0; r < 2; ++r) {
        int row = row0 + r;
        int b = row >> 6, y = (row >> 3) & 7, xx = row & 7;
        float q = emb[(size_t)fidx[r] * 256 + t];
        out[((size_t)(b * 256 + t) * 8 + y) * 8 + xx] = q;
        float diff = q - lat[r][t];
        msel += diff * diff;
    }
    #pragma unroll
    for (int s = 1; s < 64; s <<= 1) msel += __shfl_xor(msel, s);
    if (lane == 0) smse[wave] = msel;
    __syncthreads();
    if (t == 0) atomicAdd(mse_acc, smse[0] + smse[1] + smse[2] + smse[3]);
    if (t < 2) atomicAdd(&hist[fidx[t]], 1);
}

__global__ void final_k(const float* __restrict__ mse_acc, const int* __restrict__ hist,
                        float* __restrict__ out)
{
    __shared__ float sh[512];
    int t = threadIdx.x;
    float p = (float)hist[t] / 512.f;
    sh[t] = p * logf(p + 1e-10f);
    __syncthreads();
    for (int s = 256; s > 0; s >>= 1) {
        if (t < s) sh[t] += sh[t + s];
        __syncthreads();
    }
    if (t == 0) {
        float loss = 2.f * mse_acc[0] / (512.f * 256.f);
        float perp = expf(-sh[0]);
        out[131072] = loss;
        out[131073] = perp;
    }
}

// ===========================================================================
extern "C" void kernel_launch(void* const* d_in, const int* in_sizes, int n_in,
                              void* d_out, int out_size, void* d_ws, size_t ws_size,
                              hipStream_t stream)
{
    const float* x    = (const float*)d_in[0];
    const float* w_in = (const float*)d_in[1];
    const float* b_in = (const float*)d_in[2];
    const float* w_h1 = (const float*)d_in[3];
    const float* b_h1 = (const float*)d_in[4];
    const float* w_h2 = (const float*)d_in[5];
    const float* b_h2 = (const float*)d_in[6];
    const float* w_h3 = (const float*)d_in[7];
    const float* b_h3 = (const float*)d_in[8];
    const float* r0w1 = (const float*)d_in[9];
    const float* r0w2 = (const float*)d_in[10];
    const float* r1w1 = (const float*)d_in[11];
    const float* r1w2 = (const float*)d_in[12];
    const float* emb  = (const float*)d_in[13];
    float* out = (float*)d_out;

    char* ws = (char*)d_ws;
    size_t off = 0;
    auto alloc = [&](size_t bytes) -> void* {
        void* p = ws + off;
        off += (bytes + 255) & ~(size_t)255;
        return p;
    };

    float* en  = (float*)alloc(512 * 4);
    float* mse = (float*)alloc(256);
    int*  hist = (int*)alloc(512 * 4);
    float* zpad = (float*)alloc(256);
    float* p3  = (float*)alloc(4194304ull * 4);    // 8 f32 slices, 16.8 MB
    bf16* h3T  = (bf16*)alloc(524288ull * 2);
    bf16* h4T  = (bf16*)alloc(131072ull * 2);
    bf16* t1T  = (bf16*)alloc(524288ull * 2);
    bf16* h5T  = (bf16*)alloc(131072ull * 2);
    bf16* h6T  = (bf16*)alloc(131072ull * 2);
    bf16* wp1  = (bf16*)alloc(8192ull * 2);
    bf16* wpack2 = (bf16*)alloc(1638400ull * 2);
    bf16* wpack3 = (bf16*)alloc(3276800ull * 2);
    bf16* wp4  = (bf16*)alloc(589824ull * 2);
    bf16* wpA0 = (bf16*)alloc(786432ull * 2);
    bf16* wpA1 = (bf16*)alloc(786432ull * 2);
    bf16* wpB0 = (bf16*)alloc(262144ull * 2);
    bf16* wpB1 = (bf16*)alloc(262144ull * 2);
    bf16* h2c  = (bf16*)alloc(8388608ull * 2);     // [8][16 blk][4096 px][16]
    size_t base_end = off;

    const size_t H1F_B = 8388608ull * 8 * 2;       // batched h1c, 134 MB
    size_t needT1 = base_end + H1F_B + 4096;
    bf16* h1c;
    int tier;
    if (ws_size >= needT1) {
        h1c = (bf16*)alloc(H1F_B);
        tier = 1;
    } else {
        h1c = (bf16*)alloc(8388608ull * 2);
        tier = 2;
    }

    initw_k<<<3107, 256, 0, stream>>>(w_in, w_h1, w_h2, w_h3, r0w1, r0w2, r1w1, r1w2,
        emb, wp1, wpack2, wpack3, wp4, wpA0, wpA1, wpB0, wpB1, en, mse, hist, zpad);

    if (tier == 1) {
        conv1m_k<<<4096, 256, 0, stream>>>(x, wp1, b_in, h1c);
        conv_mfma9_k<256, 64, 128, 1, 0><<<512, 256, 0, stream>>>(
            h1c, wpack2, b_h1, nullptr, h2c, zpad);
    } else {
        for (int n = 0; n < 8; ++n) {
            conv1m_k<<<512, 256, 0, stream>>>(x + (size_t)n * 786432, wp1, b_in, h1c);
            conv_mfma9_k<256, 64, 128, 1, 0><<<64, 256, 0, stream>>>(
                h1c, wpack2, b_h1, nullptr, h2c + (size_t)n * 1048576, zpad);
        }
    }

    conv_mfma9_k<64, 16, 256, 8, 3><<<256, 256, 0, stream>>>(
        h2c, wpack3, nullptr, p3, nullptr, zpad);
    combine3_k<<<2048, 256, 0, stream>>>(p3, b_h2, h3T);

    conv4m_k<<<32, 256, 0, stream>>>(h3T, wp4, b_h3, h4T);
    resam_k<<<128, 256, 0, stream>>>(h4T, wpA0, t1T);
    resbm_k<<<64, 256, 0, stream>>>(h4T, t1T, wpB0, h5T);
    resam_k<<<128, 256, 0, stream>>>(h5T, wpA1, t1T);
    resbm_k<<<64, 256, 0, stream>>>(h5T, t1T, wpB1, h6T);

    vq_k<<<256, 256, 0, stream>>>(h6T, emb, en, out, mse, hist);
    final_k<<<1, 512, 0, stream>>>(mse, hist, out);
}